// Round 10
// baseline (93.666 us; speedup 1.0000x reference)
//
#include <hip/hip_runtime.h>
#include <math.h>

#define B_ 1024
#define I_ 256
#define N_ 1024
#define O_ 256
#define EPSV 1e-5f

typedef unsigned short u16;
typedef short bf16x8 __attribute__((ext_vector_type(8)));   // 8 bf16 = 4 VGPRs
typedef float f32x4 __attribute__((ext_vector_type(4)));
typedef int i32x4 __attribute__((ext_vector_type(4)));

__device__ inline u16 f2bf(float f) {
    union { float f; unsigned int u; } v; v.f = f;
    unsigned int r = v.u + 0x7FFFu + ((v.u >> 16) & 1u);   // round-to-nearest-even
    return (u16)(r >> 16);
}

// Fragment-order storage: per (row16-tile, k32-tile) store 64 chunks of 8 bf16.
// chunk slot = quad*16 + (row&15) = lane; matches MFMA A/B layout
// (m|n = lane&15, k = (lane>>4)*8 + j). Tile = 512 u16 = 1 KB.

// ---------------------------------------------------------------------------
// Transpose + convert into fragment order (R8-proven): fp32 [R][C] -> frag
// order over rows=C, k=R. One 64x64 tile. tile stride 69.
// ---------------------------------------------------------------------------
__device__ inline void transconv_frag(const float* __restrict__ in,
                                      u16* __restrict__ out, int R, int C,
                                      int r0, int c0, int t, float (*tile)[69]) {
    const int lr = t >> 2, lq = t & 3;
    #pragma unroll
    for (int j = 0; j < 4; ++j) {
        float4 v = *(const float4*)(in + (size_t)(r0 + lr) * C + c0 + lq * 16 + j * 4);
        *(float4*)&tile[lr][lq * 16 + j * 4] = v;
    }
    __syncthreads();
    const int oc = t >> 2, oq = t & 3;
    const int row = c0 + oc;
    const int ktiles = R >> 5;
    #pragma unroll
    for (int h = 0; h < 2; ++h) {
        const int k0 = r0 + oq * 16 + h * 8;
        const int kt = k0 >> 5, quad = (k0 >> 3) & 3;
        __align__(16) u16 tmp[8];
        #pragma unroll
        for (int e = 0; e < 8; ++e)
            tmp[e] = f2bf(tile[oq * 16 + h * 8 + e][oc]);
        const size_t off = ((size_t)((row >> 4) * ktiles + kt)) * 512
                         + (quad * 16 + (row & 15)) * 8;
        *(int4*)(out + off) = *(const int4*)tmp;
    }
}

// ---------------------------------------------------------------------------
// Kernel 1, 640 blocks:
//  [0,512): SELF-CONTAINED phi: stage fp32 X rows + G cols -> bf16 frag LDS,
//           compute xsq/gsq in-block, MFMA C = X@G^T (K=256), epilogue
//           phi = exp(-(xsq-2C+gsq)/max(s,eps)) -> frag-order P.
//  [512,640): W [N][O] -> WT frag-order bf16 (independent; feeds kernel 2).
// LDS: Af 32K | Bf 32K | slab 8.8K | xsq 256B | gsq 256B  = 73.2 KB
// ---------------------------------------------------------------------------
__global__ __launch_bounds__(256) void phiW_kernel(
    const float* __restrict__ x_re, const float* __restrict__ x_im,
    const float* __restrict__ G_re, const float* __restrict__ G_im,
    const float* __restrict__ W_re, const float* __restrict__ W_im,
    const float* __restrict__ s_re, const float* __restrict__ s_im,
    u16* __restrict__ WTfr, u16* __restrict__ WTfi,
    u16* __restrict__ Pfr, u16* __restrict__ Pfi)
{
    __shared__ __align__(16) char shraw[74880];
    const int blk = blockIdx.x, t = threadIdx.x;

    if (blk >= 512) {   // ---- W transpose-convert (R8 path) ----
        const int local = blk - 512;
        const int comp = local >> 6, rem = local & 63;
        const int rt = rem >> 2, ct = rem & 3;    // 16 n-tiles x 4 o-tiles
        transconv_frag(comp ? W_im : W_re, comp ? WTfi : WTfr,
                       N_, O_, rt * 64, ct * 64, t, (float(*)[69])shraw);
        return;
    }

    // ---- self-contained phi ----
    u16*   Af    = (u16*)shraw;                    // 4 mt x 8 kt tiles
    u16*   Bf    = (u16*)(shraw + 32768);          // 4 nt x 8 kt tiles
    float (*slab)[69] = (float(*)[69])(shraw + 65536);   // 32 x 69 fp32
    float* xsq_l = (float*)(shraw + 65536 + 8832);       // [64]
    float* gsq_l = xsq_l + 64;                           // [64]
    u16*   pbuf  = (u16*)(shraw + 65536);          // epilogue reuse (8 KB)

    const int z = blk >> 8, rem = blk & 255;
    const int by = rem >> 4, bx = rem & 15;
    const float* Xsrc = z ? x_im : x_re;
    const float* Gsrc = z ? G_im : G_re;
    const float* s    = z ? s_im : s_re;
    u16* Pf = z ? Pfi : Pfr;
    const int m0 = by * 64, n0 = bx * 64;

    // --- X staging: rows m0..m0+63, all K; frag-convert + xsq ---
    {
        const int lr = t >> 2, lq = t & 3;
        const float* xrow = Xsrc + (size_t)(m0 + lr) * I_;
        float xs = 0.f;
        #pragma unroll
        for (int jj = 0; jj < 4; ++jj) {
            const int k0 = jj * 64 + lq * 16;
            float4 v0 = *(const float4*)(xrow + k0);
            float4 v1 = *(const float4*)(xrow + k0 + 4);
            float4 v2 = *(const float4*)(xrow + k0 + 8);
            float4 v3 = *(const float4*)(xrow + k0 + 12);
            xs += v0.x*v0.x + v0.y*v0.y + v0.z*v0.z + v0.w*v0.w
                + v1.x*v1.x + v1.y*v1.y + v1.z*v1.z + v1.w*v1.w
                + v2.x*v2.x + v2.y*v2.y + v2.z*v2.z + v2.w*v2.w
                + v3.x*v3.x + v3.y*v3.y + v3.z*v3.z + v3.w*v3.w;
            __align__(16) u16 c0[8], c1[8];
            c0[0]=f2bf(v0.x); c0[1]=f2bf(v0.y); c0[2]=f2bf(v0.z); c0[3]=f2bf(v0.w);
            c0[4]=f2bf(v1.x); c0[5]=f2bf(v1.y); c0[6]=f2bf(v1.z); c0[7]=f2bf(v1.w);
            c1[0]=f2bf(v2.x); c1[1]=f2bf(v2.y); c1[2]=f2bf(v2.z); c1[3]=f2bf(v2.w);
            c1[4]=f2bf(v3.x); c1[5]=f2bf(v3.y); c1[6]=f2bf(v3.z); c1[7]=f2bf(v3.w);
            const int kt = k0 >> 5, quad = (k0 >> 3) & 3;
            u16* tb = Af + ((size_t)((lr >> 4) * 8 + kt)) * 512;
            *(int4*)(tb + (quad * 16 + (lr & 15)) * 8)       = *(const int4*)c0;
            *(int4*)(tb + ((quad + 1) * 16 + (lr & 15)) * 8) = *(const int4*)c1;
        }
        xs += __shfl_xor(xs, 1);
        xs += __shfl_xor(xs, 2);
        if (lq == 0) xsq_l[lr] = xs;
    }

    // --- G staging: cols n0..n0+63, all I, via 8x 32-row slab transpose ---
    {
        const int r32 = t >> 3, seg = t & 7;
        const int oc = t >> 2, oq = t & 3;
        float gs = 0.f;
        for (int sl = 0; sl < 8; ++sl) {
            const float* grow = Gsrc + (size_t)(sl * 32 + r32) * N_ + n0 + seg * 8;
            float4 g0 = *(const float4*)grow;
            float4 g1 = *(const float4*)(grow + 4);
            __syncthreads();                     // slab free from prev iter
            *(float4*)&slab[r32][seg * 8]     = g0;
            *(float4*)&slab[r32][seg * 8 + 4] = g1;
            __syncthreads();
            __align__(16) u16 tmp[8];
            #pragma unroll
            for (int e = 0; e < 8; ++e) {
                const float g = slab[oq * 8 + e][oc];
                gs += g * g;
                tmp[e] = f2bf(g);
            }
            u16* tb = Bf + ((size_t)((oc >> 4) * 8 + sl)) * 512;
            *(int4*)(tb + (oq * 16 + (oc & 15)) * 8) = *(const int4*)tmp;
        }
        gs += __shfl_xor(gs, 1);
        gs += __shfl_xor(gs, 2);
        if (oq == 0) gsq_l[oc] = gs;
        __syncthreads();   // all frags + xsq/gsq visible
    }

    // --- MFMA: 4 waves 2x2, each 32x32 via 2x2 fragments, K = 256 ---
    const int w = t >> 6, lane = t & 63;
    const int quad = lane >> 4, l16 = lane & 15;
    const int mtl = (w >> 1) * 2, ntl = (w & 1) * 2;
    const int mw = (w >> 1) * 32, nw = (w & 1) * 32;
    const u16* Abase = Af + lane * 8;
    const u16* Bbase = Bf + lane * 8;

    f32x4 acc[2][2] = {};
    #pragma unroll
    for (int kt = 0; kt < 8; ++kt) {
        bf16x8 a0 = *(const bf16x8*)(Abase + (size_t)(mtl * 8 + kt) * 512);
        bf16x8 a1 = *(const bf16x8*)(Abase + (size_t)((mtl + 1) * 8 + kt) * 512);
        bf16x8 b0 = *(const bf16x8*)(Bbase + (size_t)(ntl * 8 + kt) * 512);
        bf16x8 b1 = *(const bf16x8*)(Bbase + (size_t)((ntl + 1) * 8 + kt) * 512);
        acc[0][0] = __builtin_amdgcn_mfma_f32_16x16x32_bf16(a0, b0, acc[0][0], 0, 0, 0);
        acc[0][1] = __builtin_amdgcn_mfma_f32_16x16x32_bf16(a0, b1, acc[0][1], 0, 0, 0);
        acc[1][0] = __builtin_amdgcn_mfma_f32_16x16x32_bf16(a1, b0, acc[1][0], 0, 0, 0);
        acc[1][1] = __builtin_amdgcn_mfma_f32_16x16x32_bf16(a1, b1, acc[1][1], 0, 0, 0);
    }

    __syncthreads();   // slab region -> pbuf reuse (staging fully consumed)

    // --- Epilogue: C/D col = lane&15, row = quad*4 + reg ---
    #pragma unroll
    for (int mt = 0; mt < 2; ++mt)
        #pragma unroll
        for (int nt = 0; nt < 2; ++nt) {
            const int col = nw + nt * 16 + l16;            // local n
            const float gq = gsq_l[col];
            const float inv_s = 1.0f / fmaxf(s[n0 + col], EPSV);
            #pragma unroll
            for (int r = 0; r < 4; ++r) {
                const int row = mw + mt * 16 + quad * 4 + r;   // local m
                const float v = xsq_l[row] - 2.0f * acc[mt][nt][r] + gq;
                const u16 p = f2bf(__expf(-v * inv_s));
                const int lt = (row >> 4) * 2 + (col >> 5);
                pbuf[lt * 512 + (((col >> 3) & 3) * 16 + (row & 15)) * 8 + (col & 7)] = p;
            }
        }
    __syncthreads();

    // --- Coalesced b128 stores of frag-order P (N_/32 = 32 ktiles) ---
    const int lt = t >> 5, s32 = t & 31;
    const int mt_g = by * 4 + (lt >> 1);
    const int kt_g = bx * 2 + (lt & 1);
    const u16* src = pbuf + lt * 512 + s32 * 16;
    u16* dst = Pf + (size_t)(mt_g * 32 + kt_g) * 512 + s32 * 16;
    *(int4*)dst = *(const int4*)src;
    *((int4*)dst + 1) = *((const int4*)src + 1);
}

// ---------------------------------------------------------------------------
// Kernel 2 (R8-identical): complex GEMM, frag-direct, no atomics.
// Grid (8, 64) = 512 blocks: 16(b) x 32(o) per block; 4 waves each reduce a
// K-quarter (256) with 1x2 complex fragments + register prefetch; LDS
// cross-wave reduce + bias + coalesced float4 stores.
// ---------------------------------------------------------------------------
__global__ __launch_bounds__(256) void y_mfma(
    const u16* __restrict__ Pfr, const u16* __restrict__ Pfi,
    const u16* __restrict__ WTfr, const u16* __restrict__ WTfi,
    const float* __restrict__ b_re, const float* __restrict__ b_im,
    float* __restrict__ out)
{
    __shared__ float red[4][2][16][34];
    const int t = threadIdx.x;
    const int w = t >> 6, lane = t & 63;
    const int quad = lane >> 4, l16 = lane & 15;
    const int pm = blockIdx.y;        // P 16-row tile (32 ktiles)
    const int wo0 = blockIdx.x * 2;   // WT 16-row tiles

    const u16* Ar = Pfr + lane * 8;
    const u16* Ai = Pfi + lane * 8;
    const u16* Br = WTfr + lane * 8;
    const u16* Bi = WTfi + lane * 8;
    const size_t ao = (size_t)(pm * 32 + w * 8) * 512;
    const size_t b0o = (size_t)(wo0 * 32 + w * 8) * 512;
    const size_t b1o = (size_t)((wo0 + 1) * 32 + w * 8) * 512;

    bf16x8 cAr = *(const bf16x8*)(Ar + ao);
    bf16x8 cAi = *(const bf16x8*)(Ai + ao);
    bf16x8 cBr0 = *(const bf16x8*)(Br + b0o);
    bf16x8 cBi0 = *(const bf16x8*)(Bi + b0o);
    bf16x8 cBr1 = *(const bf16x8*)(Br + b1o);
    bf16x8 cBi1 = *(const bf16x8*)(Bi + b1o);

    f32x4 cr[2] = {}, ci[2] = {};
    #pragma unroll
    for (int ks = 0; ks < 8; ++ks) {
        bf16x8 nAr, nAi, nBr0, nBi0, nBr1, nBi1;
        if (ks < 7) {
            const size_t ko = (size_t)(ks + 1) * 512;
            nAr  = *(const bf16x8*)(Ar + ao + ko);
            nAi  = *(const bf16x8*)(Ai + ao + ko);
            nBr0 = *(const bf16x8*)(Br + b0o + ko);
            nBi0 = *(const bf16x8*)(Bi + b0o + ko);
            nBr1 = *(const bf16x8*)(Br + b1o + ko);
            nBi1 = *(const bf16x8*)(Bi + b1o + ko);
        }
        i32x4 tv = (*(const i32x4*)&cAi) ^ 0x80008000;   // negate bf16 pairs
        bf16x8 cAn = *(const bf16x8*)&tv;
        cr[0] = __builtin_amdgcn_mfma_f32_16x16x32_bf16(cAr, cBr0, cr[0], 0, 0, 0);
        cr[0] = __builtin_amdgcn_mfma_f32_16x16x32_bf16(cAn, cBi0, cr[0], 0, 0, 0);
        ci[0] = __builtin_amdgcn_mfma_f32_16x16x32_bf16(cAr, cBi0, ci[0], 0, 0, 0);
        ci[0] = __builtin_amdgcn_mfma_f32_16x16x32_bf16(cAi, cBr0, ci[0], 0, 0, 0);
        cr[1] = __builtin_amdgcn_mfma_f32_16x16x32_bf16(cAr, cBr1, cr[1], 0, 0, 0);
        cr[1] = __builtin_amdgcn_mfma_f32_16x16x32_bf16(cAn, cBi1, cr[1], 0, 0, 0);
        ci[1] = __builtin_amdgcn_mfma_f32_16x16x32_bf16(cAr, cBi1, ci[1], 0, 0, 0);
        ci[1] = __builtin_amdgcn_mfma_f32_16x16x32_bf16(cAi, cBr1, ci[1], 0, 0, 0);
        cAr = nAr; cAi = nAi;
        cBr0 = nBr0; cBi0 = nBi0; cBr1 = nBr1; cBi1 = nBi1;
    }

    // C/D: o_local = nt*16 + l16, b_local = quad*4 + r.
    #pragma unroll
    for (int nt = 0; nt < 2; ++nt) {
        const int o = nt * 16 + l16;
        #pragma unroll
        for (int r = 0; r < 4; ++r) {
            const int b = quad * 4 + r;
            red[w][0][b][o] = cr[nt][r];
            red[w][1][b][o] = ci[nt][r];
        }
    }
    __syncthreads();

    const int b = t >> 4, oq = t & 15;
    const int o = oq * 2;
    const int gb = blockIdx.y * 16 + b;
    const int go = blockIdx.x * 32 + o;
    float r0 = red[0][0][b][o]   + red[1][0][b][o]   + red[2][0][b][o]   + red[3][0][b][o];
    float i0 = red[0][1][b][o]   + red[1][1][b][o]   + red[2][1][b][o]   + red[3][1][b][o];
    float r1 = red[0][0][b][o+1] + red[1][0][b][o+1] + red[2][0][b][o+1] + red[3][0][b][o+1];
    float i1 = red[0][1][b][o+1] + red[1][1][b][o+1] + red[2][1][b][o+1] + red[3][1][b][o+1];
    float4 v;
    v.x = r0 + b_re[go];     v.y = i0 + b_im[go];
    v.z = r1 + b_re[go + 1]; v.w = i1 + b_im[go + 1];
    *(float4*)(out + ((size_t)gb * O_ + go) * 2) = v;
}

extern "C" void kernel_launch(void* const* d_in, const int* in_sizes, int n_in,
                              void* d_out, int out_size, void* d_ws, size_t ws_size,
                              hipStream_t stream) {
    const float* x_re = (const float*)d_in[0];
    const float* x_im = (const float*)d_in[1];
    const float* G_re = (const float*)d_in[2];
    const float* G_im = (const float*)d_in[3];
    const float* s_re = (const float*)d_in[4];
    const float* s_im = (const float*)d_in[5];
    const float* W_re = (const float*)d_in[6];
    const float* W_im = (const float*)d_in[7];
    const float* b_re = (const float*)d_in[8];
    const float* b_im = (const float*)d_in[9];
    float* out = (float*)d_out;

    u16* WTfr = (u16*)d_ws;                    // [O][N] frag, 512 KB
    u16* WTfi = WTfr + (size_t)O_ * N_;
    u16* Pfr  = WTfi + (size_t)O_ * N_;        // [B][N] frag, 2 MB
    u16* Pfi  = Pfr  + (size_t)B_ * N_;

    phiW_kernel<<<640, 256, 0, stream>>>(
        x_re, x_im, G_re, G_im, W_re, W_im, s_re, s_im,
        WTfr, WTfi, Pfr, Pfi);

    y_mfma<<<dim3(O_ / 32, B_ / 16), 256, 0, stream>>>(
        Pfr, Pfi, WTfr, WTfi, b_re, b_im, out);
}

// Round 11
// 90.447 us; speedup vs baseline: 1.0356x; 1.0356x over previous
//
#include <hip/hip_runtime.h>
#include <math.h>

#define B_ 1024
#define I_ 256
#define N_ 1024
#define O_ 256
#define EPSV 1e-5f

typedef unsigned short u16;
typedef short bf16x8 __attribute__((ext_vector_type(8)));   // 8 bf16 = 4 VGPRs
typedef float f32x4 __attribute__((ext_vector_type(4)));
typedef int i32x4 __attribute__((ext_vector_type(4)));

__device__ inline u16 f2bf(float f) {
    union { float f; unsigned int u; } v; v.f = f;
    unsigned int r = v.u + 0x7FFFu + ((v.u >> 16) & 1u);   // round-to-nearest-even
    return (u16)(r >> 16);
}

// Fragment-order storage: per (row16-tile, k32-tile) store 64 chunks of 8 bf16.
// chunk slot = quad*16 + (row&15) = lane; matches MFMA A/B layout
// (m|n = lane&15, k = (lane>>4)*8 + j). Tile = 512 u16 = 1 KB.

// ---------------------------------------------------------------------------
// Transpose + convert into fragment order; optionally accumulate column
// sum-of-squares partials into gpart[(r0/64)*C + col] (no atomics).
// ---------------------------------------------------------------------------
__device__ inline void transconv_frag(const float* __restrict__ in,
                                      u16* __restrict__ out, int R, int C,
                                      int r0, int c0, int t, float (*tile)[69],
                                      float* __restrict__ gpart) {
    const int lr = t >> 2, lq = t & 3;
    #pragma unroll
    for (int j = 0; j < 4; ++j) {
        float4 v = *(const float4*)(in + (size_t)(r0 + lr) * C + c0 + lq * 16 + j * 4);
        *(float4*)&tile[lr][lq * 16 + j * 4] = v;
    }
    __syncthreads();
    const int oc = t >> 2, oq = t & 3;
    const int row = c0 + oc;
    const int ktiles = R >> 5;
    float ss = 0.f;
    #pragma unroll
    for (int h = 0; h < 2; ++h) {
        const int k0 = r0 + oq * 16 + h * 8;
        const int kt = k0 >> 5, quad = (k0 >> 3) & 3;
        __align__(16) u16 tmp[8];
        #pragma unroll
        for (int e = 0; e < 8; ++e) {
            const float g = tile[oq * 16 + h * 8 + e][oc];
            ss += g * g;
            tmp[e] = f2bf(g);
        }
        const size_t off = ((size_t)((row >> 4) * ktiles + kt)) * 512
                         + (quad * 16 + (row & 15)) * 8;
        *(int4*)(out + off) = *(const int4*)tmp;
    }
    if (gpart) {
        ss += __shfl_xor(ss, 1);
        ss += __shfl_xor(ss, 2);
        if (oq == 0) gpart[(r0 >> 6) * C + row] = ss;
    }
}

// ---------------------------------------------------------------------------
// Fused prep (R8-identical), 288 uniform blocks:
//   [0,32):    X fp32 -> frag bf16 + xsq (1 wave per (comp, 16-row tile))
//   [32,160):  G [I][N] -> GT frag + gsq partials [4][N]
//   [160,288): W [N][O] -> WT frag
// ---------------------------------------------------------------------------
__global__ __launch_bounds__(256) void prep_kernel(
    const float* __restrict__ x_re, const float* __restrict__ x_im,
    const float* __restrict__ G_re, const float* __restrict__ G_im,
    const float* __restrict__ W_re, const float* __restrict__ W_im,
    u16* __restrict__ Xfr, u16* __restrict__ Xfi,
    u16* __restrict__ GTfr, u16* __restrict__ GTfi,
    u16* __restrict__ WTfr, u16* __restrict__ WTfi,
    float* __restrict__ xsq_re, float* __restrict__ xsq_im,
    float* __restrict__ gsq_re_part, float* __restrict__ gsq_im_part)
{
    __shared__ float smem[64][69];
    const int blk = blockIdx.x, t = threadIdx.x;

    if (blk < 32) {
        const int unit = blk * 4 + (t >> 6);     // comp x 64 m-tiles
        const int comp = unit >> 6, mt = unit & 63;
        const int lane = t & 63;
        const int l16 = lane & 15, quad = lane >> 4;
        const float* src = (comp ? x_im : x_re)
                         + (size_t)(mt * 16 + l16) * I_ + quad * 8;
        u16* dstbase = (comp ? Xfi : Xfr) + (size_t)(mt * 8) * 512 + lane * 8;
        float ssum = 0.f;
        #pragma unroll
        for (int kt = 0; kt < 8; ++kt) {
            float4 a0 = *(const float4*)(src + kt * 32);
            float4 a1 = *(const float4*)(src + kt * 32 + 4);
            ssum += a0.x*a0.x + a0.y*a0.y + a0.z*a0.z + a0.w*a0.w
                  + a1.x*a1.x + a1.y*a1.y + a1.z*a1.z + a1.w*a1.w;
            __align__(16) u16 tmp[8];
            tmp[0] = f2bf(a0.x); tmp[1] = f2bf(a0.y);
            tmp[2] = f2bf(a0.z); tmp[3] = f2bf(a0.w);
            tmp[4] = f2bf(a1.x); tmp[5] = f2bf(a1.y);
            tmp[6] = f2bf(a1.z); tmp[7] = f2bf(a1.w);
            *(int4*)(dstbase + (size_t)kt * 512) = *(const int4*)tmp;
        }
        ssum += __shfl_xor(ssum, 16);
        ssum += __shfl_xor(ssum, 32);
        if (lane < 16) {
            float* xsq = comp ? xsq_im : xsq_re;
            xsq[mt * 16 + lane] = ssum;
        }
    } else if (blk < 160) {
        const int local = blk - 32;
        const int comp = local >> 6, rem = local & 63;
        const int rt = rem >> 4, ct = rem & 15;
        transconv_frag(comp ? G_im : G_re, comp ? GTfi : GTfr,
                       I_, N_, rt * 64, ct * 64, t, smem,
                       comp ? gsq_im_part : gsq_re_part);
    } else {
        const int local = blk - 160;
        const int comp = local >> 6, rem = local & 63;
        const int rt = rem >> 2, ct = rem & 3;
        transconv_frag(comp ? W_im : W_re, comp ? WTfi : WTfr,
                       N_, O_, rt * 64, ct * 64, t, smem, (float*)0);
    }
}

// ---------------------------------------------------------------------------
// phi GEMM, higher occupancy: 32x64 tile, grid (16, 32, 2) = 1024 blocks
// (4 blocks/CU = 4 waves/SIMD). 4 waves 2x2 of 16x32 wave-tiles; per wave
// 1 A-frag x 2 B-frags per kt (3 loads, 2 MFMAs), register prefetch.
// Epilogue -> frag-order P via 4 KB LDS + coalesced b128 stores.
// ---------------------------------------------------------------------------
__global__ __launch_bounds__(256) void phi_mfma(
    const u16* __restrict__ Xfr, const u16* __restrict__ Xfi,
    const u16* __restrict__ GTfr, const u16* __restrict__ GTfi,
    const float* __restrict__ xsq_re, const float* __restrict__ xsq_im,
    const float* __restrict__ gsq_re_part, const float* __restrict__ gsq_im_part,
    const float* __restrict__ s_re, const float* __restrict__ s_im,
    u16* __restrict__ Pfr, u16* __restrict__ Pfi)
{
    __shared__ u16 pbuf[4 * 512];   // 4 KB: 2 mt x 2 kt P tiles
    const int z = blockIdx.z;
    const u16* Xf  = z ? Xfi : Xfr;
    const u16* GTf = z ? GTfi : GTfr;
    const float* xsq = z ? xsq_im : xsq_re;
    const float* gp  = z ? gsq_im_part : gsq_re_part;
    const float* s   = z ? s_im : s_re;
    u16* Pf = z ? Pfi : Pfr;

    const int t = threadIdx.x;
    const int w = t >> 6, lane = t & 63;
    const int quad = lane >> 4, l16 = lane & 15;
    const int wm = w >> 1, wn = w & 1;            // wave tile: 16m x 32n
    const int by = blockIdx.y, bx = blockIdx.x;
    const int mt_g = by * 2 + wm;                 // global X 16-row tile
    const int nt0 = bx * 4 + wn * 2;              // global GT 16-row tiles

    const u16* Ab = Xf  + lane * 8;
    const u16* Bb = GTf + lane * 8;
    const size_t ao  = (size_t)(mt_g * 8) * 512;
    const size_t b0o = (size_t)(nt0 * 8) * 512;
    const size_t b1o = (size_t)((nt0 + 1) * 8) * 512;

    bf16x8 cA  = *(const bf16x8*)(Ab + ao);
    bf16x8 cB0 = *(const bf16x8*)(Bb + b0o);
    bf16x8 cB1 = *(const bf16x8*)(Bb + b1o);

    f32x4 acc[2] = {};
    #pragma unroll
    for (int kt = 0; kt < 8; ++kt) {
        bf16x8 nA, nB0, nB1;
        if (kt < 7) {
            const size_t ko = (size_t)(kt + 1) * 512;
            nA  = *(const bf16x8*)(Ab + ao + ko);
            nB0 = *(const bf16x8*)(Bb + b0o + ko);
            nB1 = *(const bf16x8*)(Bb + b1o + ko);
        }
        acc[0] = __builtin_amdgcn_mfma_f32_16x16x32_bf16(cA, cB0, acc[0], 0, 0, 0);
        acc[1] = __builtin_amdgcn_mfma_f32_16x16x32_bf16(cA, cB1, acc[1], 0, 0, 0);
        cA = nA; cB0 = nB0; cB1 = nB1;
    }

    // Epilogue. C/D: col = lane&15, row = quad*4 + reg. Local coords in 32x64.
    const int m0 = by * 32, n0 = bx * 64;
    #pragma unroll
    for (int nt = 0; nt < 2; ++nt) {
        const int col = wn * 32 + nt * 16 + l16;       // [0,64)
        const int gn = n0 + col;
        const float gq = gp[gn] + gp[N_ + gn] + gp[2 * N_ + gn] + gp[3 * N_ + gn];
        const float inv_s = 1.0f / fmaxf(s[gn], EPSV);
        #pragma unroll
        for (int r = 0; r < 4; ++r) {
            const int row = wm * 16 + quad * 4 + r;    // [0,32)
            const float v = xsq[m0 + row] - 2.0f * acc[nt][r] + gq;
            const u16 p = f2bf(__expf(-v * inv_s));
            const int lt = (row >> 4) * 2 + (col >> 5);
            pbuf[lt * 512 + (((col >> 3) & 3) * 16 + (row & 15)) * 8 + (col & 7)] = p;
        }
    }
    __syncthreads();

    // Coalesced b128 stores (P has N_/32 = 32 ktiles). 4 tiles x 64 threads.
    const int lt = t >> 6, s64 = t & 63;
    const int mt_o = by * 2 + (lt >> 1);
    const int kt_o = bx * 2 + (lt & 1);
    const u16* src = pbuf + lt * 512 + s64 * 8;
    u16* dst = Pf + (size_t)(mt_o * 32 + kt_o) * 512 + s64 * 8;
    *(int4*)dst = *(const int4*)src;
}

// ---------------------------------------------------------------------------
// Complex GEMM, higher occupancy: 512 blocks x 512 threads (8 waves/block,
// 4 waves/SIMD at 2 blocks/CU). Each block 16(b) x 32(o); 8 waves each
// reduce a K-eighth (128) with 1x2 complex fragments + register prefetch;
// LDS cross-wave reduce (8 partials, 34.8 KB) + bias + float4 stores.
// ---------------------------------------------------------------------------
__global__ __launch_bounds__(512) void y_mfma(
    const u16* __restrict__ Pfr, const u16* __restrict__ Pfi,
    const u16* __restrict__ WTfr, const u16* __restrict__ WTfi,
    const float* __restrict__ b_re, const float* __restrict__ b_im,
    float* __restrict__ out)
{
    __shared__ float red[8][2][16][34];
    const int t = threadIdx.x;
    const int w = t >> 6, lane = t & 63;
    const int quad = lane >> 4, l16 = lane & 15;
    const int pm = blockIdx.y;        // P 16-row tile (32 ktiles)
    const int wo0 = blockIdx.x * 2;   // WT 16-row tiles

    const u16* Ar = Pfr + lane * 8;
    const u16* Ai = Pfi + lane * 8;
    const u16* Br = WTfr + lane * 8;
    const u16* Bi = WTfi + lane * 8;
    const size_t ao  = (size_t)(pm * 32 + w * 4) * 512;
    const size_t b0o = (size_t)(wo0 * 32 + w * 4) * 512;
    const size_t b1o = (size_t)((wo0 + 1) * 32 + w * 4) * 512;

    bf16x8 cAr = *(const bf16x8*)(Ar + ao);
    bf16x8 cAi = *(const bf16x8*)(Ai + ao);
    bf16x8 cBr0 = *(const bf16x8*)(Br + b0o);
    bf16x8 cBi0 = *(const bf16x8*)(Bi + b0o);
    bf16x8 cBr1 = *(const bf16x8*)(Br + b1o);
    bf16x8 cBi1 = *(const bf16x8*)(Bi + b1o);

    f32x4 cr[2] = {}, ci[2] = {};
    #pragma unroll
    for (int ks = 0; ks < 4; ++ks) {
        bf16x8 nAr, nAi, nBr0, nBi0, nBr1, nBi1;
        if (ks < 3) {
            const size_t ko = (size_t)(ks + 1) * 512;
            nAr  = *(const bf16x8*)(Ar + ao + ko);
            nAi  = *(const bf16x8*)(Ai + ao + ko);
            nBr0 = *(const bf16x8*)(Br + b0o + ko);
            nBi0 = *(const bf16x8*)(Bi + b0o + ko);
            nBr1 = *(const bf16x8*)(Br + b1o + ko);
            nBi1 = *(const bf16x8*)(Bi + b1o + ko);
        }
        i32x4 tv = (*(const i32x4*)&cAi) ^ 0x80008000;   // negate bf16 pairs
        bf16x8 cAn = *(const bf16x8*)&tv;
        cr[0] = __builtin_amdgcn_mfma_f32_16x16x32_bf16(cAr, cBr0, cr[0], 0, 0, 0);
        cr[0] = __builtin_amdgcn_mfma_f32_16x16x32_bf16(cAn, cBi0, cr[0], 0, 0, 0);
        ci[0] = __builtin_amdgcn_mfma_f32_16x16x32_bf16(cAr, cBi0, ci[0], 0, 0, 0);
        ci[0] = __builtin_amdgcn_mfma_f32_16x16x32_bf16(cAi, cBr0, ci[0], 0, 0, 0);
        cr[1] = __builtin_amdgcn_mfma_f32_16x16x32_bf16(cAr, cBr1, cr[1], 0, 0, 0);
        cr[1] = __builtin_amdgcn_mfma_f32_16x16x32_bf16(cAn, cBi1, cr[1], 0, 0, 0);
        ci[1] = __builtin_amdgcn_mfma_f32_16x16x32_bf16(cAr, cBi1, ci[1], 0, 0, 0);
        ci[1] = __builtin_amdgcn_mfma_f32_16x16x32_bf16(cAi, cBr1, ci[1], 0, 0, 0);
        cAr = nAr; cAi = nAi;
        cBr0 = nBr0; cBi0 = nBi0; cBr1 = nBr1; cBi1 = nBi1;
    }

    // C/D: o_local = nt*16 + l16, b_local = quad*4 + r.
    #pragma unroll
    for (int nt = 0; nt < 2; ++nt) {
        const int o = nt * 16 + l16;
        #pragma unroll
        for (int r = 0; r < 4; ++r) {
            const int b = quad * 4 + r;
            red[w][0][b][o] = cr[nt][r];
            red[w][1][b][o] = ci[nt][r];
        }
    }
    __syncthreads();

    if (t < 256) {
        const int b = t >> 4, oq = t & 15;
        const int o = oq * 2;
        const int gb = blockIdx.y * 16 + b;
        const int go = blockIdx.x * 32 + o;
        float r0 = 0.f, i0 = 0.f, r1 = 0.f, i1 = 0.f;
        #pragma unroll
        for (int ww = 0; ww < 8; ++ww) {
            r0 += red[ww][0][b][o];     i0 += red[ww][1][b][o];
            r1 += red[ww][0][b][o + 1]; i1 += red[ww][1][b][o + 1];
        }
        float4 v;
        v.x = r0 + b_re[go];     v.y = i0 + b_im[go];
        v.z = r1 + b_re[go + 1]; v.w = i1 + b_im[go + 1];
        *(float4*)(out + ((size_t)gb * O_ + go) * 2) = v;
    }
}

extern "C" void kernel_launch(void* const* d_in, const int* in_sizes, int n_in,
                              void* d_out, int out_size, void* d_ws, size_t ws_size,
                              hipStream_t stream) {
    const float* x_re = (const float*)d_in[0];
    const float* x_im = (const float*)d_in[1];
    const float* G_re = (const float*)d_in[2];
    const float* G_im = (const float*)d_in[3];
    const float* s_re = (const float*)d_in[4];
    const float* s_im = (const float*)d_in[5];
    const float* W_re = (const float*)d_in[6];
    const float* W_im = (const float*)d_in[7];
    const float* b_re = (const float*)d_in[8];
    const float* b_im = (const float*)d_in[9];
    float* out = (float*)d_out;

    u16* Xfr  = (u16*)d_ws;
    u16* Xfi  = Xfr  + (size_t)B_ * I_;
    u16* GTfr = Xfi  + (size_t)B_ * I_;
    u16* GTfi = GTfr + (size_t)N_ * I_;
    u16* WTfr = GTfi + (size_t)N_ * I_;
    u16* WTfi = WTfr + (size_t)O_ * N_;
    u16* Pfr  = WTfi + (size_t)O_ * N_;
    u16* Pfi  = Pfr  + (size_t)B_ * N_;
    float* xsq_re = (float*)(Pfi + (size_t)B_ * N_);
    float* xsq_im = xsq_re + B_;
    float* gsq_re_part = xsq_im + B_;        // [4][N_]
    float* gsq_im_part = gsq_re_part + 4 * N_;

    prep_kernel<<<288, 256, 0, stream>>>(
        x_re, x_im, G_re, G_im, W_re, W_im,
        Xfr, Xfi, GTfr, GTfi, WTfr, WTfi,
        xsq_re, xsq_im, gsq_re_part, gsq_im_part);

    phi_mfma<<<dim3(N_ / 64, B_ / 32, 2), 256, 0, stream>>>(
        Xfr, Xfi, GTfr, GTfi, xsq_re, xsq_im, gsq_re_part, gsq_im_part,
        s_re, s_im, Pfr, Pfi);

    y_mfma<<<dim3(O_ / 32, B_ / 16), 512, 0, stream>>>(
        Pfr, Pfi, WTfr, WTfi, b_re, b_im, out);
}